// Round 3
// baseline (537.611 us; speedup 1.0000x reference)
//
#include <hip/hip_runtime.h>

// GAT layer, N=8192, F_IN=256, F_OUT=128.
// K1 wh: Wh = h@W (fp32 VALU) + WhT (f16 transposed [c][j]).  512 blocks.
// K2 f12: f1 = Wh@a1, f2 = Wh@a2.
// K3 attn: RPB=16 (was 32) so per-thread state fits 128 VGPR with NO spill:
//   acc[8] (32 regs) + bfr[8] (32) + adj prefetch (16). 2048 blocks
//   (512 row-groups x JSPLIT=4), 4-5 blocks/CU resident. adj straight from
//   HBM as per-thread int4, depth-1 register prefetch; bfr issued first so
//   MFMA waits leave the adj prefetch in flight across the back-edge.
//   f2 staged once in LDS. No in-loop barriers.
// K4 comb: sum 4 partials / sum 4 spart.

#define N_NODES 8192
#define F_IN 256
#define F_OUT 128
#define RPB 16                      // rows per block
#define JCH 128                     // j per chunk (per iteration)
#define JSPLIT 4
#define JRANGE (N_NODES / JSPLIT)   // 2048
#define NCH (JRANGE / JCH)          // 16 iterations

typedef _Float16 half8 __attribute__((ext_vector_type(8)));
typedef float floatx4 __attribute__((ext_vector_type(4)));
typedef float f32x4 __attribute__((ext_vector_type(4)));

__device__ __align__(16) float g_Wh[N_NODES * F_OUT];                  // 4 MB
__device__ __align__(16) _Float16 g_WhT[(size_t)F_OUT * N_NODES];      // 2 MB
__device__ __align__(16) float g_f1[N_NODES];
__device__ __align__(16) float g_f2[N_NODES];
__device__ __align__(16) float g_part[JSPLIT][N_NODES * F_OUT];        // 16 MB
__device__ __align__(16) float g_spart[JSPLIT][N_NODES];               // 128 KB

// ---------------- Kernel A: Wh = h @ W ----------------
__global__ __launch_bounds__(256, 2) void wh_kernel(
    const float* __restrict__ h, const float* __restrict__ W) {
  __shared__ float hT[F_IN][20];  // pad 20 keeps &hT[k][rg*8] 16B-aligned
  const int t = threadIdx.x;
  const int i0 = blockIdx.x * 16;
  {
    const int row = t >> 4;   // 0..15
    const int fu = t & 15;    // float4 unit
#pragma unroll
    for (int r = 0; r < 4; ++r) {
      const int ku = r * 16 + fu;  // 0..63
      const float4 v = *(const float4*)(h + (size_t)(i0 + row) * F_IN + ku * 4);
      hT[ku * 4 + 0][row] = v.x; hT[ku * 4 + 1][row] = v.y;
      hT[ku * 4 + 2][row] = v.z; hT[ku * 4 + 3][row] = v.w;
    }
  }
  __syncthreads();
  const int c = t & 127;
  const int rg = t >> 7;   // 8 rows per thread
  float acc[8];
#pragma unroll
  for (int r = 0; r < 8; ++r) acc[r] = 0.f;
#pragma unroll 8
  for (int k = 0; k < F_IN; ++k) {
    const float wv = W[k * F_OUT + c];
    const float4 x0 = *(const float4*)(&hT[k][rg * 8]);      // lane-uniform -> broadcast
    const float4 x1 = *(const float4*)(&hT[k][rg * 8 + 4]);
    acc[0] = fmaf(x0.x, wv, acc[0]); acc[1] = fmaf(x0.y, wv, acc[1]);
    acc[2] = fmaf(x0.z, wv, acc[2]); acc[3] = fmaf(x0.w, wv, acc[3]);
    acc[4] = fmaf(x1.x, wv, acc[4]); acc[5] = fmaf(x1.y, wv, acc[5]);
    acc[6] = fmaf(x1.z, wv, acc[6]); acc[7] = fmaf(x1.w, wv, acc[7]);
  }
#pragma unroll
  for (int r = 0; r < 8; ++r)
    g_Wh[(size_t)(i0 + rg * 8 + r) * F_OUT + c] = acc[r];
  union { _Float16 hh[8]; uint4 u4; } pk;
#pragma unroll
  for (int r = 0; r < 8; ++r) pk.hh[r] = (_Float16)acc[r];
  *(uint4*)(g_WhT + (size_t)c * N_NODES + i0 + rg * 8) = pk.u4;
}

// ---------------- Kernel B: f1 = Wh@a1, f2 = Wh@a2 ----------------
__global__ __launch_bounds__(256) void f12_kernel(const float* __restrict__ a) {
  const int t = threadIdx.x;
  const int row = blockIdx.x * 2 + (t >> 7);
  const int c = t & 127;
  const float wh = g_Wh[(size_t)row * F_OUT + c];
  float p1 = wh * a[c];
  float p2 = wh * a[F_OUT + c];
  for (int o = 32; o > 0; o >>= 1) {
    p1 += __shfl_down(p1, o, 64);
    p2 += __shfl_down(p2, o, 64);
  }
  __shared__ float s1[4], s2[4];
  const int w = t >> 6;
  if ((t & 63) == 0) { s1[w] = p1; s2[w] = p2; }
  __syncthreads();
  if ((t & 127) == 0) {
    g_f1[row] = s1[w] + s1[w + 1];
    g_f2[row] = s2[w] + s2[w + 1];
  }
}

// ---------------- Kernel C: fused attention (partials) ----------------
__device__ __forceinline__ float score_p(int a, float f2v, float f1r) {
  float s = f1r + f2v;
  s = fmaxf(s, 0.2f * s);  // leaky_relu, alpha=0.2<1
  float arg = (a > 0) ? fmaf(s, 1.44269504088896f, -16.0f) : -1.0e5f;
  return __builtin_amdgcn_exp2f(arg);  // masked -> 0; 2^-16 scale cancels in num/den
}

__global__ __launch_bounds__(256, 4) void gat_attn_kernel(const int* __restrict__ adj) {
  const int t = threadIdx.x;
  const int wave = t >> 6;
  const int lane = t & 63;
  const int mrow = lane & 15;
  const int quad = lane >> 4;
  const int i0 = blockIdx.x * RPB;
  const int js = blockIdx.y;
  const int jbase = js * JRANGE;

  __shared__ float ldsF2[JRANGE];        // 8 KB, whole j-quarter of f2
  __shared__ float ldsO[RPB][F_OUT];     // 8 KB
  __shared__ float ldsS[4][RPB];

  // runtime C/D layout probe: D1[m][n]=m, D2[m][n]=n (self-correcting scatter)
  int rm[4], cm[4];
  {
    half8 a1f, b1f, a2f, b2f;
#pragma unroll
    for (int e = 0; e < 8; ++e) {
      a1f[e] = (_Float16)0; b1f[e] = (_Float16)0;
      a2f[e] = (_Float16)0; b2f[e] = (_Float16)0;
    }
    if (quad == 0) {
      a1f[0] = (_Float16)mrow; b1f[0] = (_Float16)1;
      a2f[0] = (_Float16)1;    b2f[0] = (_Float16)mrow;
    }
    floatx4 d1 = (floatx4)0.f, d2 = (floatx4)0.f;
    d1 = __builtin_amdgcn_mfma_f32_16x16x32_f16(a1f, b1f, d1, 0, 0, 0);
    d2 = __builtin_amdgcn_mfma_f32_16x16x32_f16(a2f, b2f, d2, 0, 0, 0);
#pragma unroll
    for (int r = 0; r < 4; ++r) { rm[r] = (int)d1[r]; cm[r] = (int)d2[r]; }
  }

  const float f1r0 = g_f1[i0 + mrow];

  half8 ones;
#pragma unroll
  for (int e = 0; e < 8; ++e) ones[e] = (_Float16)1;

  floatx4 acc[8];
  floatx4 asum = (floatx4)0.f;
#pragma unroll
  for (int ct = 0; ct < 8; ++ct) acc[ct] = (floatx4)0.f;

  // stage the f2 quarter once (x16-row reuse justifies LDS; adj has none)
#pragma unroll
  for (int it = 0; it < 2; ++it) {
    const int u = it * 256 + t;
    *(float4*)&ldsF2[u * 4] = *(const float4*)(g_f2 + jbase + u * 4);
  }
  __syncthreads();

  const size_t rowoff0 = (size_t)(i0 + mrow) * N_NODES;
  const int jloc = wave * 32 + quad * 8;

  // prologue: adj for c=0 in registers
  int4 A00 = *(const int4*)(adj + rowoff0 + jbase + jloc);
  int4 A01 = *(const int4*)(adj + rowoff0 + jbase + jloc + 4);

#pragma unroll 1
  for (int c = 0; c < NCH; ++c) {
    const int jglob = jbase + c * JCH + jloc;

    // B-frags from L2 direct to VGPR. Issued FIRST: the MFMA's wait on these
    // leaves the adj prefetch below still in flight across the back-edge.
    half8 bfr[8];
#pragma unroll
    for (int ct = 0; ct < 8; ++ct)
      bfr[ct] = *(const half8*)(g_WhT + (size_t)(ct * 16 + mrow) * N_NODES + jglob);

    // adj prefetch for iteration c+1 (depth-1 register double buffer).
    // Last iteration re-loads c=0 (clamped), values unused.
    const int jn = jbase + ((c + 1 < NCH) ? (c + 1) : 0) * JCH + jloc;
    const int4 nA00 = *(const int4*)(adj + rowoff0 + jn);
    const int4 nA01 = *(const int4*)(adj + rowoff0 + jn + 4);

    const float4 F0 = *(const float4*)&ldsF2[c * JCH + jloc];
    const float4 F1 = *(const float4*)&ldsF2[c * JCH + jloc + 4];

    // scores from A (in registers since last iteration -> no memory wait)
    half8 af0;
    af0[0] = (_Float16)score_p(A00.x, F0.x, f1r0);
    af0[1] = (_Float16)score_p(A00.y, F0.y, f1r0);
    af0[2] = (_Float16)score_p(A00.z, F0.z, f1r0);
    af0[3] = (_Float16)score_p(A00.w, F0.w, f1r0);
    af0[4] = (_Float16)score_p(A01.x, F1.x, f1r0);
    af0[5] = (_Float16)score_p(A01.y, F1.y, f1r0);
    af0[6] = (_Float16)score_p(A01.z, F1.z, f1r0);
    af0[7] = (_Float16)score_p(A01.w, F1.w, f1r0);

#pragma unroll
    for (int ct = 0; ct < 8; ++ct)
      acc[ct] = __builtin_amdgcn_mfma_f32_16x16x32_f16(af0, bfr[ct], acc[ct], 0, 0, 0);
    asum = __builtin_amdgcn_mfma_f32_16x16x32_f16(af0, ones, asum, 0, 0, 0);

    // rotate prefetch registers (compiler renames, no moves)
    A00 = nA00; A01 = nA01;
    // no barrier, no waitcnt(0): waves free-run
  }

  // psum per row (all cols of asum equal; take the 4 probed rows per quad)
  if (mrow == 0) {
#pragma unroll
    for (int r = 0; r < 4; ++r)
      ldsS[wave][rm[r]] = asum[r];
  }
  // serialized wave-add of the 16x128 tile
  for (int w = 0; w < 4; ++w) {
    if (wave == w) {
#pragma unroll
      for (int ct = 0; ct < 8; ++ct)
#pragma unroll
        for (int r = 0; r < 4; ++r) {
          float* p = &ldsO[rm[r]][ct * 16 + cm[r]];
          if (w == 0) *p = acc[ct][r];
          else        *p += acc[ct][r];
        }
    }
    __syncthreads();
  }
  {
    const int row = t >> 4;         // 16 threads per row
    const int c0 = (t & 15) * 8;
    float* dst = g_part[js] + (size_t)(i0 + row) * F_OUT + c0;
    *(f32x4*)(dst)     = *(const f32x4*)(&ldsO[row][c0]);
    *(f32x4*)(dst + 4) = *(const f32x4*)(&ldsO[row][c0 + 4]);
    if (t < RPB)
      g_spart[js][i0 + t] = ldsS[0][t] + ldsS[1][t] + ldsS[2][t] + ldsS[3][t];
  }
}

// ---------------- Kernel D: combine partials + normalize ----------------
__global__ __launch_bounds__(256) void comb_kernel(float* __restrict__ out) {
  const int u = blockIdx.x * 256 + threadIdx.x;  // float4 unit
  const int row = u >> 5;                        // 32 float4 per row
  const float s = g_spart[0][row] + g_spart[1][row] +
                  g_spart[2][row] + g_spart[3][row];
  const f32x4 v = ((const f32x4*)g_part[0])[u] + ((const f32x4*)g_part[1])[u] +
                  ((const f32x4*)g_part[2])[u] + ((const f32x4*)g_part[3])[u];
  ((f32x4*)out)[u] = v * (1.0f / s);
}

extern "C" void kernel_launch(void* const* d_in, const int* in_sizes, int n_in,
                              void* d_out, int out_size, void* d_ws, size_t ws_size,
                              hipStream_t stream) {
  const float* h = (const float*)d_in[0];
  const int* adj = (const int*)d_in[1];
  const float* W = (const float*)d_in[2];
  const float* a = (const float*)d_in[3];
  float* out = (float*)d_out;
  (void)d_ws; (void)ws_size;

  wh_kernel<<<dim3(N_NODES / 16), dim3(256), 0, stream>>>(h, W);
  f12_kernel<<<dim3(N_NODES / 2), dim3(256), 0, stream>>>(a);
  gat_attn_kernel<<<dim3(N_NODES / RPB, JSPLIT), dim3(256), 0, stream>>>(adj);
  comb_kernel<<<dim3(N_NODES * F_OUT / 4 / 256), dim3(256), 0, stream>>>(out);
}

// Round 4
// 472.061 us; speedup vs baseline: 1.1389x; 1.1389x over previous
//
#include <hip/hip_runtime.h>

// GAT layer, N=8192, F_IN=256, F_OUT=128.
// K0 pack: adj (268 MB int32, 1 bit of info/elem) -> g_bits (8 MB), read fully
//   coalesced ONCE at streaming BW. Tiled layout: byte for 8-j chunk b
//   (cg=b>>4, w=(b>>2)&3, q=b&3) lives at row*1024 + (w*4+q)*64 + cg, so each
//   attn thread's bits for 4 consecutive iterations are one aligned dword.
// K1 wh: Wh = h@W (fp32 VALU) + WhT (f16 transposed [c][j]).  512 blocks.
// K2 f12: f1 = Wh@a1, f2 = Wh@a2.
// K3 attn: round-1 structure (RPB=32, JSPLIT=2, barrier-free) but adj comes
//   from the 8 MB L2/L3-resident bitmask (1 dword per 4 iters per row) -> the
//   DRAM-page-thrashing 268 MB adj stream is gone. launch_bounds (256,3):
//   no spill, no forced load serialization (round-3 lesson).
// K4 comb: (part0+part1)/(s0+s1).

#define N_NODES 8192
#define F_IN 256
#define F_OUT 128
#define RPB 32                      // rows per block
#define JCH 128                     // j per chunk (per iteration)
#define JSPLIT 2
#define JRANGE (N_NODES / JSPLIT)   // 4096
#define NCH (JRANGE / JCH)          // 32 iterations

typedef _Float16 half8 __attribute__((ext_vector_type(8)));
typedef float floatx4 __attribute__((ext_vector_type(4)));
typedef float f32x4 __attribute__((ext_vector_type(4)));

__device__ __align__(16) float g_Wh[N_NODES * F_OUT];                  // 4 MB
__device__ __align__(16) _Float16 g_WhT[(size_t)F_OUT * N_NODES];      // 2 MB
__device__ __align__(16) float g_f1[N_NODES];
__device__ __align__(16) float g_f2[N_NODES];
__device__ __align__(16) float g_part[JSPLIT][N_NODES * F_OUT];        // 8 MB
__device__ __align__(16) float g_spart[JSPLIT][N_NODES];               // 64 KB
__device__ __align__(16) unsigned char g_bits[(size_t)N_NODES * (N_NODES / 8)]; // 8 MB

// ---------------- Kernel 0: pack adj -> bitmask (tiled) ----------------
__global__ __launch_bounds__(256) void pack_kernel(const int* __restrict__ adj) {
  const int t = threadIdx.x;
  const int wave = t >> 6;
  const int lane = t & 63;
  const int row0 = blockIdx.x * 8 + wave * 2;
#pragma unroll 1
  for (int rr = 0; rr < 2; ++rr) {
    const int r = row0 + rr;
    const int* rowp = adj + (size_t)r * N_NODES;
#pragma unroll 4
    for (int p = 0; p < 16; ++p) {
      const int j0 = p * 512 + lane * 8;   // wave reads 2 KB contiguous/pass
      const int4 v0 = *(const int4*)(rowp + j0);
      const int4 v1 = *(const int4*)(rowp + j0 + 4);
      unsigned int byte = 0;
      byte |= (v0.x != 0) ? 1u : 0u;
      byte |= (v0.y != 0) ? 2u : 0u;
      byte |= (v0.z != 0) ? 4u : 0u;
      byte |= (v0.w != 0) ? 8u : 0u;
      byte |= (v1.x != 0) ? 16u : 0u;
      byte |= (v1.y != 0) ? 32u : 0u;
      byte |= (v1.z != 0) ? 64u : 0u;
      byte |= (v1.w != 0) ? 128u : 0u;
      const int b = p * 64 + lane;         // 8-j chunk index within row
      const int addr = r * 1024 + (((b >> 2) & 3) * 4 + (b & 3)) * 64 + (b >> 4);
      g_bits[addr] = (unsigned char)byte;  // per-lane scatter, 8 MB total
    }
  }
}

// ---------------- Kernel A: Wh = h @ W ----------------
__global__ __launch_bounds__(256, 2) void wh_kernel(
    const float* __restrict__ h, const float* __restrict__ W) {
  __shared__ float hT[F_IN][20];  // pad 20 keeps &hT[k][rg*8] 16B-aligned
  const int t = threadIdx.x;
  const int i0 = blockIdx.x * 16;
  {
    const int row = t >> 4;   // 0..15
    const int fu = t & 15;    // float4 unit
#pragma unroll
    for (int r = 0; r < 4; ++r) {
      const int ku = r * 16 + fu;  // 0..63
      const float4 v = *(const float4*)(h + (size_t)(i0 + row) * F_IN + ku * 4);
      hT[ku * 4 + 0][row] = v.x; hT[ku * 4 + 1][row] = v.y;
      hT[ku * 4 + 2][row] = v.z; hT[ku * 4 + 3][row] = v.w;
    }
  }
  __syncthreads();
  const int c = t & 127;
  const int rg = t >> 7;   // 8 rows per thread
  float acc[8];
#pragma unroll
  for (int r = 0; r < 8; ++r) acc[r] = 0.f;
#pragma unroll 8
  for (int k = 0; k < F_IN; ++k) {
    const float wv = W[k * F_OUT + c];
    const float4 x0 = *(const float4*)(&hT[k][rg * 8]);      // lane-uniform -> broadcast
    const float4 x1 = *(const float4*)(&hT[k][rg * 8 + 4]);
    acc[0] = fmaf(x0.x, wv, acc[0]); acc[1] = fmaf(x0.y, wv, acc[1]);
    acc[2] = fmaf(x0.z, wv, acc[2]); acc[3] = fmaf(x0.w, wv, acc[3]);
    acc[4] = fmaf(x1.x, wv, acc[4]); acc[5] = fmaf(x1.y, wv, acc[5]);
    acc[6] = fmaf(x1.z, wv, acc[6]); acc[7] = fmaf(x1.w, wv, acc[7]);
  }
#pragma unroll
  for (int r = 0; r < 8; ++r)
    g_Wh[(size_t)(i0 + rg * 8 + r) * F_OUT + c] = acc[r];
  union { _Float16 hh[8]; uint4 u4; } pk;
#pragma unroll
  for (int r = 0; r < 8; ++r) pk.hh[r] = (_Float16)acc[r];
  *(uint4*)(g_WhT + (size_t)c * N_NODES + i0 + rg * 8) = pk.u4;
}

// ---------------- Kernel B: f1 = Wh@a1, f2 = Wh@a2 ----------------
__global__ __launch_bounds__(256) void f12_kernel(const float* __restrict__ a) {
  const int t = threadIdx.x;
  const int row = blockIdx.x * 2 + (t >> 7);
  const int c = t & 127;
  const float wh = g_Wh[(size_t)row * F_OUT + c];
  float p1 = wh * a[c];
  float p2 = wh * a[F_OUT + c];
  for (int o = 32; o > 0; o >>= 1) {
    p1 += __shfl_down(p1, o, 64);
    p2 += __shfl_down(p2, o, 64);
  }
  __shared__ float s1[4], s2[4];
  const int w = t >> 6;
  if ((t & 63) == 0) { s1[w] = p1; s2[w] = p2; }
  __syncthreads();
  if ((t & 127) == 0) {
    g_f1[row] = s1[w] + s1[w + 1];
    g_f2[row] = s2[w] + s2[w + 1];
  }
}

// ---------------- Kernel C: fused attention (partials) ----------------
__device__ __forceinline__ float score_b(unsigned int bit, float f2v, float f1r) {
  float s = f1r + f2v;
  s = fmaxf(s, 0.2f * s);  // leaky_relu, alpha=0.2<1
  float arg = bit ? fmaf(s, 1.44269504088896f, -16.0f) : -1.0e5f;
  return __builtin_amdgcn_exp2f(arg);  // masked -> 0; 2^-16 scale cancels in num/den
}

__global__ __launch_bounds__(256, 3) void gat_attn_kernel() {
  const int t = threadIdx.x;
  const int wave = t >> 6;
  const int lane = t & 63;
  const int mrow = lane & 15;
  const int quad = lane >> 4;
  const int i0 = blockIdx.x * RPB;
  const int js = blockIdx.y;
  const int jbase = js * JRANGE;

  __shared__ float ldsF2[JRANGE];        // 16 KB, whole j-half of f2
  __shared__ float ldsO[RPB][F_OUT];     // 16 KB
  __shared__ float ldsS[4][RPB];

  // runtime C/D layout probe: D1[m][n]=m, D2[m][n]=n (self-correcting scatter)
  int rm[4], cm[4];
  {
    half8 a1f, b1f, a2f, b2f;
#pragma unroll
    for (int e = 0; e < 8; ++e) {
      a1f[e] = (_Float16)0; b1f[e] = (_Float16)0;
      a2f[e] = (_Float16)0; b2f[e] = (_Float16)0;
    }
    if (quad == 0) {
      a1f[0] = (_Float16)mrow; b1f[0] = (_Float16)1;
      a2f[0] = (_Float16)1;    b2f[0] = (_Float16)mrow;
    }
    floatx4 d1 = (floatx4)0.f, d2 = (floatx4)0.f;
    d1 = __builtin_amdgcn_mfma_f32_16x16x32_f16(a1f, b1f, d1, 0, 0, 0);
    d2 = __builtin_amdgcn_mfma_f32_16x16x32_f16(a2f, b2f, d2, 0, 0, 0);
#pragma unroll
    for (int r = 0; r < 4; ++r) { rm[r] = (int)d1[r]; cm[r] = (int)d2[r]; }
  }

  const float f1r0 = g_f1[i0 + mrow];
  const float f1r1 = g_f1[i0 + 16 + mrow];

  half8 ones;
#pragma unroll
  for (int e = 0; e < 8; ++e) ones[e] = (_Float16)1;

  floatx4 acc[2][8];
  floatx4 asum[2];
#pragma unroll
  for (int tl = 0; tl < 2; ++tl) {
    asum[tl] = (floatx4)0.f;
#pragma unroll
    for (int ct = 0; ct < 8; ++ct) acc[tl][ct] = (floatx4)0.f;
  }

  // stage the f2 half once (x32-row reuse justifies LDS)
#pragma unroll
  for (int it = 0; it < 4; ++it) {
    const int u = it * 256 + t;
    *(float4*)&ldsF2[u * 4] = *(const float4*)(g_f2 + jbase + u * 4);
  }
  __syncthreads();

  const int wq = wave * 4 + quad;
  const int jloc = wave * 32 + quad * 8;
  // bitmask pointers: all adj info for this thread's (row, wave, quad, js)
  // lives in 32 contiguous bytes -> 1 dword per 4 iterations.
  const unsigned char* bp0 = g_bits + (i0 + mrow) * 1024 + wq * 64 + js * 32;
  const unsigned char* bp1 = g_bits + (i0 + 16 + mrow) * 1024 + wq * 64 + js * 32;

#pragma unroll 1
  for (int c4 = 0; c4 < NCH / 4; ++c4) {
    const unsigned int dw0 = *(const unsigned int*)(bp0 + c4 * 4);
    const unsigned int dw1 = *(const unsigned int*)(bp1 + c4 * 4);
#pragma unroll
    for (int k = 0; k < 4; ++k) {
      const int c = c4 * 4 + k;
      const int jglob = jbase + c * JCH + jloc;

      // B-frags from L2 direct to VGPR
      half8 bfr[8];
#pragma unroll
      for (int ct = 0; ct < 8; ++ct)
        bfr[ct] = *(const half8*)(g_WhT + (size_t)(ct * 16 + mrow) * N_NODES + jglob);

      const float4 F0 = *(const float4*)&ldsF2[c * JCH + jloc];
      const float4 F1 = *(const float4*)&ldsF2[c * JCH + jloc + 4];

      const unsigned int b0 = (dw0 >> (8 * k)) & 0xffu;  // static shift (k unrolled)
      const unsigned int b1 = (dw1 >> (8 * k)) & 0xffu;

      half8 af0, af1;
      af0[0] = (_Float16)score_b(b0 & 1u,   F0.x, f1r0);
      af0[1] = (_Float16)score_b(b0 & 2u,   F0.y, f1r0);
      af0[2] = (_Float16)score_b(b0 & 4u,   F0.z, f1r0);
      af0[3] = (_Float16)score_b(b0 & 8u,   F0.w, f1r0);
      af0[4] = (_Float16)score_b(b0 & 16u,  F1.x, f1r0);
      af0[5] = (_Float16)score_b(b0 & 32u,  F1.y, f1r0);
      af0[6] = (_Float16)score_b(b0 & 64u,  F1.z, f1r0);
      af0[7] = (_Float16)score_b(b0 & 128u, F1.w, f1r0);
      af1[0] = (_Float16)score_b(b1 & 1u,   F0.x, f1r1);
      af1[1] = (_Float16)score_b(b1 & 2u,   F0.y, f1r1);
      af1[2] = (_Float16)score_b(b1 & 4u,   F0.z, f1r1);
      af1[3] = (_Float16)score_b(b1 & 8u,   F0.w, f1r1);
      af1[4] = (_Float16)score_b(b1 & 16u,  F1.x, f1r1);
      af1[5] = (_Float16)score_b(b1 & 32u,  F1.y, f1r1);
      af1[6] = (_Float16)score_b(b1 & 64u,  F1.z, f1r1);
      af1[7] = (_Float16)score_b(b1 & 128u, F1.w, f1r1);

#pragma unroll
      for (int ct = 0; ct < 8; ++ct) {
        acc[0][ct] = __builtin_amdgcn_mfma_f32_16x16x32_f16(af0, bfr[ct], acc[0][ct], 0, 0, 0);
        acc[1][ct] = __builtin_amdgcn_mfma_f32_16x16x32_f16(af1, bfr[ct], acc[1][ct], 0, 0, 0);
      }
      asum[0] = __builtin_amdgcn_mfma_f32_16x16x32_f16(af0, ones, asum[0], 0, 0, 0);
      asum[1] = __builtin_amdgcn_mfma_f32_16x16x32_f16(af1, ones, asum[1], 0, 0, 0);
      // no barrier, no waitcnt: waves free-run
    }
  }

  // psum per row (all cols of asum equal; take the 4 probed rows per quad)
  if (mrow == 0) {
#pragma unroll
    for (int tl = 0; tl < 2; ++tl)
#pragma unroll
      for (int r = 0; r < 4; ++r)
        ldsS[wave][tl * 16 + rm[r]] = asum[tl][r];
  }
  // serialized wave-add of the 32x128 tile
  for (int w = 0; w < 4; ++w) {
    if (wave == w) {
#pragma unroll
      for (int tl = 0; tl < 2; ++tl)
#pragma unroll
        for (int ct = 0; ct < 8; ++ct)
#pragma unroll
          for (int r = 0; r < 4; ++r) {
            float* p = &ldsO[tl * 16 + rm[r]][ct * 16 + cm[r]];
            if (w == 0) *p = acc[tl][ct][r];
            else        *p += acc[tl][ct][r];
          }
    }
    __syncthreads();
  }
  {
    const int row = t >> 3;
    const int c0 = (t & 7) * 16;
    float* dst = g_part[js] + (size_t)(i0 + row) * F_OUT + c0;
#pragma unroll
    for (int q = 0; q < 4; ++q)
      *(f32x4*)(dst + q * 4) = *(const f32x4*)(&ldsO[row][c0 + q * 4]);
    if (t < RPB)
      g_spart[js][i0 + t] = ldsS[0][t] + ldsS[1][t] + ldsS[2][t] + ldsS[3][t];
  }
}

// ---------------- Kernel D: combine partials + normalize ----------------
__global__ __launch_bounds__(256) void comb_kernel(float* __restrict__ out) {
  const int u = blockIdx.x * 256 + threadIdx.x;  // float4 unit
  const int row = u >> 5;                        // 32 float4 per row
  const float s = g_spart[0][row] + g_spart[1][row];
  const f32x4 v = ((const f32x4*)g_part[0])[u] + ((const f32x4*)g_part[1])[u];
  ((f32x4*)out)[u] = v * (1.0f / s);
}

extern "C" void kernel_launch(void* const* d_in, const int* in_sizes, int n_in,
                              void* d_out, int out_size, void* d_ws, size_t ws_size,
                              hipStream_t stream) {
  const float* h = (const float*)d_in[0];
  const int* adj = (const int*)d_in[1];
  const float* W = (const float*)d_in[2];
  const float* a = (const float*)d_in[3];
  float* out = (float*)d_out;
  (void)d_ws; (void)ws_size;

  pack_kernel<<<dim3(N_NODES / 8), dim3(256), 0, stream>>>(adj);
  wh_kernel<<<dim3(N_NODES / 16), dim3(256), 0, stream>>>(h, W);
  f12_kernel<<<dim3(N_NODES / 2), dim3(256), 0, stream>>>(a);
  gat_attn_kernel<<<dim3(N_NODES / RPB, JSPLIT), dim3(256), 0, stream>>>();
  comb_kernel<<<dim3(N_NODES * F_OUT / 4 / 256), dim3(256), 0, stream>>>(out);
}

// Round 5
// 470.293 us; speedup vs baseline: 1.1431x; 1.0038x over previous
//
#include <hip/hip_runtime.h>

// GAT layer, N=8192, F_IN=256, F_OUT=128.
// K0 prep (role-split, pack || wh co-run):
//   blocks 0..1023: pack adj (268 MB, 1 bit info/elem) -> g_bits (8 MB),
//     nontemporal loads (don't evict L2), tiled layout so each attn thread's
//     bits for 4 consecutive iters are one aligned dword.
//   blocks 1024..1535: Wh = h@W (fp32 VALU) + WhT (f16 [c][j]) + f1/f2
//     reduction fused on the register tail (f12 kernel eliminated).
// K1 attn: RPB=32, JSPLIT=4 with XCD-PINNED js (js = blockIdx.x & 3; since
//   xcd = flat%8, each XCD serves exactly one js quarter -> its WhT working
//   set is 512 KB, permanently L2-resident; no thrash from other js halves).
//   bits via nt dword loads, g_part stores nt. Barrier-free main loop.
// K2 comb: sum 4 partials / sum 4 spart, nt streaming.

#define N_NODES 8192
#define F_IN 256
#define F_OUT 128
#define RPB 32                      // rows per block
#define JCH 128                     // j per chunk (per iteration)
#define JSPLIT 4
#define JRANGE (N_NODES / JSPLIT)   // 2048
#define NCH (JRANGE / JCH)          // 16 iterations

typedef _Float16 half8 __attribute__((ext_vector_type(8)));
typedef float floatx4 __attribute__((ext_vector_type(4)));
typedef float f32x4 __attribute__((ext_vector_type(4)));
typedef int intx4 __attribute__((ext_vector_type(4)));

__device__ __align__(16) float g_Wh[N_NODES * F_OUT];                  // 4 MB
__device__ __align__(16) _Float16 g_WhT[(size_t)F_OUT * N_NODES];      // 2 MB
__device__ __align__(16) float g_f1[N_NODES];
__device__ __align__(16) float g_f2[N_NODES];
__device__ __align__(16) float g_part[JSPLIT][N_NODES * F_OUT];        // 16 MB
__device__ __align__(16) float g_spart[JSPLIT][N_NODES];               // 128 KB
__device__ __align__(16) unsigned char g_bits[(size_t)N_NODES * (N_NODES / 8)]; // 8 MB

// ---------------- Kernel 0: pack(adj->bits) || wh(+f12) ----------------
__global__ __launch_bounds__(256, 2) void prep_kernel(
    const int* __restrict__ adj, const float* __restrict__ h,
    const float* __restrict__ W, const float* __restrict__ a) {
  const int t = threadIdx.x;
  const int bid = blockIdx.x;

  if (bid < N_NODES / 8) {
    // ---- pack role: 8 rows per block, fully coalesced nt reads ----
    const int wave = t >> 6;
    const int lane = t & 63;
    const int row0 = bid * 8 + wave * 2;
#pragma unroll 1
    for (int rr = 0; rr < 2; ++rr) {
      const int r = row0 + rr;
      const int* rowp = adj + (size_t)r * N_NODES;
#pragma unroll 4
      for (int p = 0; p < 16; ++p) {
        const int j0 = p * 512 + lane * 8;   // wave reads 2 KB contiguous/pass
        const intx4 v0 = __builtin_nontemporal_load((const intx4*)(rowp + j0));
        const intx4 v1 = __builtin_nontemporal_load((const intx4*)(rowp + j0 + 4));
        unsigned int byte = 0;
        byte |= (v0.x != 0) ? 1u : 0u;
        byte |= (v0.y != 0) ? 2u : 0u;
        byte |= (v0.z != 0) ? 4u : 0u;
        byte |= (v0.w != 0) ? 8u : 0u;
        byte |= (v1.x != 0) ? 16u : 0u;
        byte |= (v1.y != 0) ? 32u : 0u;
        byte |= (v1.z != 0) ? 64u : 0u;
        byte |= (v1.w != 0) ? 128u : 0u;
        const int b = p * 64 + lane;         // 8-j chunk index within row
        const int addr = r * 1024 + (((b >> 2) & 3) * 4 + (b & 3)) * 64 + (b >> 4);
        g_bits[addr] = (unsigned char)byte;
      }
    }
    return;
  }

  // ---- wh role: 16 rows per block + fused f1/f2 ----
  __shared__ float hT[F_IN][20];  // pad 20 keeps &hT[k][rg*8] 16B-aligned
  __shared__ float fs[2][2][8][2];
  const int i0 = (bid - N_NODES / 8) * 16;
  {
    const int row = t >> 4;   // 0..15
    const int fu = t & 15;    // float4 unit
#pragma unroll
    for (int r = 0; r < 4; ++r) {
      const int ku = r * 16 + fu;  // 0..63
      const f32x4 v = __builtin_nontemporal_load(
          (const f32x4*)(h + (size_t)(i0 + row) * F_IN + ku * 4));
      hT[ku * 4 + 0][row] = v.x; hT[ku * 4 + 1][row] = v.y;
      hT[ku * 4 + 2][row] = v.z; hT[ku * 4 + 3][row] = v.w;
    }
  }
  __syncthreads();
  const int c = t & 127;
  const int rg = t >> 7;   // 8 rows per thread
  float acc[8];
#pragma unroll
  for (int r = 0; r < 8; ++r) acc[r] = 0.f;
#pragma unroll 8
  for (int k = 0; k < F_IN; ++k) {
    const float wv = W[k * F_OUT + c];
    const float4 x0 = *(const float4*)(&hT[k][rg * 8]);      // lane-uniform -> broadcast
    const float4 x1 = *(const float4*)(&hT[k][rg * 8 + 4]);
    acc[0] = fmaf(x0.x, wv, acc[0]); acc[1] = fmaf(x0.y, wv, acc[1]);
    acc[2] = fmaf(x0.z, wv, acc[2]); acc[3] = fmaf(x0.w, wv, acc[3]);
    acc[4] = fmaf(x1.x, wv, acc[4]); acc[5] = fmaf(x1.y, wv, acc[5]);
    acc[6] = fmaf(x1.z, wv, acc[6]); acc[7] = fmaf(x1.w, wv, acc[7]);
  }
#pragma unroll
  for (int r = 0; r < 8; ++r)
    g_Wh[(size_t)(i0 + rg * 8 + r) * F_OUT + c] = acc[r];
  union { _Float16 hh[8]; uint4 u4; } pk;
#pragma unroll
  for (int r = 0; r < 8; ++r) pk.hh[r] = (_Float16)acc[r];
  *(uint4*)(g_WhT + (size_t)c * N_NODES + i0 + rg * 8) = pk.u4;

  // fused f12: f1[row] = sum_c Wh[row][c]*a1[c]  (rows live in acc[])
  const float a1c = a[c];
  const float a2c = a[F_OUT + c];
  float p1[8], p2[8];
#pragma unroll
  for (int r = 0; r < 8; ++r) { p1[r] = acc[r] * a1c; p2[r] = acc[r] * a2c; }
#pragma unroll
  for (int o = 32; o > 0; o >>= 1)
#pragma unroll
    for (int r = 0; r < 8; ++r) {
      p1[r] += __shfl_down(p1[r], o, 64);
      p2[r] += __shfl_down(p2[r], o, 64);
    }
  const int wv = t >> 6;
  const int lane = t & 63;
  if (lane == 0) {
#pragma unroll
    for (int r = 0; r < 8; ++r) {
      fs[wv >> 1][wv & 1][r][0] = p1[r];
      fs[wv >> 1][wv & 1][r][1] = p2[r];
    }
  }
  __syncthreads();
  if (t < 16) {
    const int rg2 = t >> 3, r2 = t & 7;
    g_f1[i0 + rg2 * 8 + r2] = fs[rg2][0][r2][0] + fs[rg2][1][r2][0];
    g_f2[i0 + rg2 * 8 + r2] = fs[rg2][0][r2][1] + fs[rg2][1][r2][1];
  }
}

// ---------------- Kernel C: fused attention (partials) ----------------
__device__ __forceinline__ float score_b(unsigned int bit, float f2v, float f1r) {
  float s = f1r + f2v;
  s = fmaxf(s, 0.2f * s);  // leaky_relu, alpha=0.2<1
  float arg = bit ? fmaf(s, 1.44269504088896f, -16.0f) : -1.0e5f;
  return __builtin_amdgcn_exp2f(arg);  // masked -> 0; 2^-16 scale cancels in num/den
}

__global__ __launch_bounds__(256, 2) void gat_attn_kernel() {
  const int t = threadIdx.x;
  const int wave = t >> 6;
  const int lane = t & 63;
  const int mrow = lane & 15;
  const int quad = lane >> 4;
  const int flat = blockIdx.x;
  const int js = flat & 3;            // xcd = flat%8 -> js = xcd&3: one js/XCD
  const int i0 = (flat >> 2) * RPB;
  const int jbase = js * JRANGE;

  __shared__ float ldsF2[JRANGE];        // 8 KB, whole j-quarter of f2
  __shared__ float ldsO[RPB][F_OUT];     // 16 KB
  __shared__ float ldsS[4][RPB];

  // runtime C/D layout probe: D1[m][n]=m, D2[m][n]=n (self-correcting scatter)
  int rm[4], cm[4];
  {
    half8 a1f, b1f, a2f, b2f;
#pragma unroll
    for (int e = 0; e < 8; ++e) {
      a1f[e] = (_Float16)0; b1f[e] = (_Float16)0;
      a2f[e] = (_Float16)0; b2f[e] = (_Float16)0;
    }
    if (quad == 0) {
      a1f[0] = (_Float16)mrow; b1f[0] = (_Float16)1;
      a2f[0] = (_Float16)1;    b2f[0] = (_Float16)mrow;
    }
    floatx4 d1 = (floatx4)0.f, d2 = (floatx4)0.f;
    d1 = __builtin_amdgcn_mfma_f32_16x16x32_f16(a1f, b1f, d1, 0, 0, 0);
    d2 = __builtin_amdgcn_mfma_f32_16x16x32_f16(a2f, b2f, d2, 0, 0, 0);
#pragma unroll
    for (int r = 0; r < 4; ++r) { rm[r] = (int)d1[r]; cm[r] = (int)d2[r]; }
  }

  const float f1r0 = g_f1[i0 + mrow];
  const float f1r1 = g_f1[i0 + 16 + mrow];

  half8 ones;
#pragma unroll
  for (int e = 0; e < 8; ++e) ones[e] = (_Float16)1;

  floatx4 acc[2][8];
  floatx4 asum[2];
#pragma unroll
  for (int tl = 0; tl < 2; ++tl) {
    asum[tl] = (floatx4)0.f;
#pragma unroll
    for (int ct = 0; ct < 8; ++ct) acc[tl][ct] = (floatx4)0.f;
  }

  // stage the f2 quarter once (x32-row reuse justifies LDS)
#pragma unroll
  for (int it = 0; it < 2; ++it) {
    const int u = it * 256 + t;
    *(float4*)&ldsF2[u * 4] = *(const float4*)(g_f2 + jbase + u * 4);
  }
  __syncthreads();

  const int wq = wave * 4 + quad;
  const int jloc = wave * 32 + quad * 8;
  // bitmask pointers: this thread's adj info for its (row, wq, js) is 16
  // contiguous bytes -> 1 dword per 4 iterations.
  const unsigned char* bp0 = g_bits + (i0 + mrow) * 1024 + wq * 64 + js * (JRANGE / 128);
  const unsigned char* bp1 = g_bits + (i0 + 16 + mrow) * 1024 + wq * 64 + js * (JRANGE / 128);

#pragma unroll 1
  for (int c4 = 0; c4 < NCH / 4; ++c4) {
    const unsigned int dw0 =
        __builtin_nontemporal_load((const unsigned int*)(bp0 + c4 * 4));
    const unsigned int dw1 =
        __builtin_nontemporal_load((const unsigned int*)(bp1 + c4 * 4));
#pragma unroll
    for (int k = 0; k < 4; ++k) {
      const int c = c4 * 4 + k;
      const int jglob = jbase + c * JCH + jloc;

      // B-frags from (now-resident) L2 direct to VGPR
      half8 bfr[8];
#pragma unroll
      for (int ct = 0; ct < 8; ++ct)
        bfr[ct] = *(const half8*)(g_WhT + (size_t)(ct * 16 + mrow) * N_NODES + jglob);

      const float4 F0 = *(const float4*)&ldsF2[c * JCH + jloc];
      const float4 F1 = *(const float4*)&ldsF2[c * JCH + jloc + 4];

      const unsigned int b0 = (dw0 >> (8 * k)) & 0xffu;  // static shift (k unrolled)
      const unsigned int b1 = (dw1 >> (8 * k)) & 0xffu;

      half8 af0, af1;
      af0[0] = (_Float16)score_b(b0 & 1u,   F0.x, f1r0);
      af0[1] = (_Float16)score_b(b0 & 2u,   F0.y, f1r0);
      af0[2] = (_Float16)score_b(b0 & 4u,   F0.z, f1r0);
      af0[3] = (_Float16)score_b(b0 & 8u,   F0.w, f1r0);
      af0[4] = (_Float16)score_b(b0 & 16u,  F1.x, f1r0);
      af0[5] = (_Float16)score_b(b0 & 32u,  F1.y, f1r0);
      af0[6] = (_Float16)score_b(b0 & 64u,  F1.z, f1r0);
      af0[7] = (_Float16)score_b(b0 & 128u, F1.w, f1r0);
      af1[0] = (_Float16)score_b(b1 & 1u,   F0.x, f1r1);
      af1[1] = (_Float16)score_b(b1 & 2u,   F0.y, f1r1);
      af1[2] = (_Float16)score_b(b1 & 4u,   F0.z, f1r1);
      af1[3] = (_Float16)score_b(b1 & 8u,   F0.w, f1r1);
      af1[4] = (_Float16)score_b(b1 & 16u,  F1.x, f1r1);
      af1[5] = (_Float16)score_b(b1 & 32u,  F1.y, f1r1);
      af1[6] = (_Float16)score_b(b1 & 64u,  F1.z, f1r1);
      af1[7] = (_Float16)score_b(b1 & 128u, F1.w, f1r1);

#pragma unroll
      for (int ct = 0; ct < 8; ++ct) {
        acc[0][ct] = __builtin_amdgcn_mfma_f32_16x16x32_f16(af0, bfr[ct], acc[0][ct], 0, 0, 0);
        acc[1][ct] = __builtin_amdgcn_mfma_f32_16x16x32_f16(af1, bfr[ct], acc[1][ct], 0, 0, 0);
      }
      asum[0] = __builtin_amdgcn_mfma_f32_16x16x32_f16(af0, ones, asum[0], 0, 0, 0);
      asum[1] = __builtin_amdgcn_mfma_f32_16x16x32_f16(af1, ones, asum[1], 0, 0, 0);
      // no barrier, no waitcnt: waves free-run
    }
  }

  // psum per row (all cols of asum equal; take the 4 probed rows per quad)
  if (mrow == 0) {
#pragma unroll
    for (int tl = 0; tl < 2; ++tl)
#pragma unroll
      for (int r = 0; r < 4; ++r)
        ldsS[wave][tl * 16 + rm[r]] = asum[tl][r];
  }
  // serialized wave-add of the 32x128 tile
  for (int w = 0; w < 4; ++w) {
    if (wave == w) {
#pragma unroll
      for (int tl = 0; tl < 2; ++tl)
#pragma unroll
        for (int ct = 0; ct < 8; ++ct)
#pragma unroll
          for (int r = 0; r < 4; ++r) {
            float* p = &ldsO[tl * 16 + rm[r]][ct * 16 + cm[r]];
            if (w == 0) *p = acc[tl][ct][r];
            else        *p += acc[tl][ct][r];
          }
    }
    __syncthreads();
  }
  {
    const int row = t >> 3;
    const int c0 = (t & 7) * 16;
    float* dst = g_part[js] + (size_t)(i0 + row) * F_OUT + c0;
#pragma unroll
    for (int q = 0; q < 4; ++q)
      __builtin_nontemporal_store(*(const f32x4*)(&ldsO[row][c0 + q * 4]),
                                  (f32x4*)(dst + q * 4));
    if (t < RPB)
      g_spart[js][i0 + t] = ldsS[0][t] + ldsS[1][t] + ldsS[2][t] + ldsS[3][t];
  }
}

// ---------------- Kernel D: combine partials + normalize ----------------
__global__ __launch_bounds__(256) void comb_kernel(float* __restrict__ out) {
  const int u = blockIdx.x * 256 + threadIdx.x;  // float4 unit
  const int row = u >> 5;                        // 32 float4 per row
  const float s = g_spart[0][row] + g_spart[1][row] +
                  g_spart[2][row] + g_spart[3][row];
  const f32x4 v = __builtin_nontemporal_load(((const f32x4*)g_part[0]) + u) +
                  __builtin_nontemporal_load(((const f32x4*)g_part[1]) + u) +
                  __builtin_nontemporal_load(((const f32x4*)g_part[2]) + u) +
                  __builtin_nontemporal_load(((const f32x4*)g_part[3]) + u);
  __builtin_nontemporal_store(v * (1.0f / s), ((f32x4*)out) + u);
}

extern "C" void kernel_launch(void* const* d_in, const int* in_sizes, int n_in,
                              void* d_out, int out_size, void* d_ws, size_t ws_size,
                              hipStream_t stream) {
  const float* h = (const float*)d_in[0];
  const int* adj = (const int*)d_in[1];
  const float* W = (const float*)d_in[2];
  const float* a = (const float*)d_in[3];
  float* out = (float*)d_out;
  (void)d_ws; (void)ws_size;

  prep_kernel<<<dim3(N_NODES / 8 + N_NODES / 16), dim3(256), 0, stream>>>(adj, h, W, a);
  gat_attn_kernel<<<dim3((N_NODES / RPB) * JSPLIT), dim3(256), 0, stream>>>();
  comb_kernel<<<dim3(N_NODES * F_OUT / 4 / 256), dim3(256), 0, stream>>>(out);
}

// Round 6
// 431.966 us; speedup vs baseline: 1.2446x; 1.0887x over previous
//
#include <hip/hip_runtime.h>

// GAT layer, N=8192, F_IN=256, F_OUT=128.
// K0 prep (role-interleaved by bid%3 so pack(memory) || wh(VALU) co-run):
//   pack: adj (268 MB, 1 bit info/elem) -> g_bits (8 MB), nt coalesced reads.
//     Layout: byte for j-chunk b of row r at r*1024 + (b&3)*256 + (b>>2), so an
//     attn thread's 8 chunk-bytes for its (row, quad, jt) are one aligned uint2.
//   wh: Wh = h@W (fp32 VALU) -> WhT (f16 [c][j]) + f1/f2 fused reduction.
// K1 attn: ZERO in-loop global loads (rounds 1-5 lesson: the per-iteration
//   L2->MFMA dependency was the 119 us floor; occupancy/pinning never fixed it).
//   Block = j-tile of 256 cols x 256 rows (8 waves x 32 rows, disjoint -> no
//   cross-wave reduce). WhT[128][256] f16 staged to LDS once (padded stride 264
//   halfs, even bank spread), f2 tile 1 KB, per-thread adj bits = one uint2,
//   f1 scalars -- all before one barrier. Loop: 8 unrolled chunks of pure
//   {ds_read B-frags, score VALU, MFMA}. Epilogue: direct stores to g_part[jt].
// K2 comb: sum 32 partial slices / sum 32 spart.

#define N_NODES 8192
#define F_IN 256
#define F_OUT 128
#define NJT 32            // j-tiles
#define JTW 256           // j-tile width
#define NCH 8             // 32-wide chunks per tile
#define LDS_STRIDE 264    // 256 + 8 halfs pad (row*33+unit spreads banks)

typedef _Float16 half8 __attribute__((ext_vector_type(8)));
typedef float floatx4 __attribute__((ext_vector_type(4)));
typedef float f32x4 __attribute__((ext_vector_type(4)));
typedef int intx4 __attribute__((ext_vector_type(4)));

__device__ __align__(16) _Float16 g_WhT[(size_t)F_OUT * N_NODES];      // 2 MB
__device__ __align__(16) float g_f1[N_NODES];
__device__ __align__(16) float g_f2[N_NODES];
__device__ __align__(16) float g_part[NJT][N_NODES * F_OUT];           // 128 MB
__device__ __align__(16) float g_spart[NJT][N_NODES];                  // 1 MB
__device__ __align__(16) unsigned char g_bits[(size_t)N_NODES * (N_NODES / 8)]; // 8 MB

// ---------------- Kernel 0: pack(adj->bits) || wh(+f12) ----------------
__global__ __launch_bounds__(256, 2) void prep_kernel(
    const int* __restrict__ adj, const float* __restrict__ h,
    const float* __restrict__ W, const float* __restrict__ a) {
  const int t = threadIdx.x;
  const int bid = blockIdx.x;

  if (bid % 3 != 0) {
    // ---- pack role: 8 rows per block, fully coalesced nt reads ----
    const int pid = bid - (bid + 2) / 3;   // 0..1023
    const int wave = t >> 6;
    const int lane = t & 63;
    const int row0 = pid * 8 + wave * 2;
#pragma unroll 1
    for (int rr = 0; rr < 2; ++rr) {
      const int r = row0 + rr;
      const int* rowp = adj + (size_t)r * N_NODES;
#pragma unroll 4
      for (int p = 0; p < 16; ++p) {
        const int j0 = p * 512 + lane * 8;   // wave reads 2 KB contiguous/pass
        const intx4 v0 = __builtin_nontemporal_load((const intx4*)(rowp + j0));
        const intx4 v1 = __builtin_nontemporal_load((const intx4*)(rowp + j0 + 4));
        unsigned int byte = 0;
        byte |= (v0.x != 0) ? 1u : 0u;
        byte |= (v0.y != 0) ? 2u : 0u;
        byte |= (v0.z != 0) ? 4u : 0u;
        byte |= (v0.w != 0) ? 8u : 0u;
        byte |= (v1.x != 0) ? 16u : 0u;
        byte |= (v1.y != 0) ? 32u : 0u;
        byte |= (v1.z != 0) ? 64u : 0u;
        byte |= (v1.w != 0) ? 128u : 0u;
        const int b = p * 64 + lane;         // 8-j chunk index within row
        g_bits[(size_t)r * 1024 + (b & 3) * 256 + (b >> 2)] = (unsigned char)byte;
      }
    }
    return;
  }

  // ---- wh role: 16 rows per block + fused f1/f2 ----
  __shared__ float hT[F_IN][20];  // pad 20 keeps &hT[k][rg*8] 16B-aligned
  __shared__ float fs[2][2][8][2];
  const int i0 = (bid / 3) * 16;
  {
    const int row = t >> 4;   // 0..15
    const int fu = t & 15;    // float4 unit
#pragma unroll
    for (int r = 0; r < 4; ++r) {
      const int ku = r * 16 + fu;  // 0..63
      const f32x4 v = __builtin_nontemporal_load(
          (const f32x4*)(h + (size_t)(i0 + row) * F_IN + ku * 4));
      hT[ku * 4 + 0][row] = v.x; hT[ku * 4 + 1][row] = v.y;
      hT[ku * 4 + 2][row] = v.z; hT[ku * 4 + 3][row] = v.w;
    }
  }
  __syncthreads();
  const int c = t & 127;
  const int rg = t >> 7;   // 8 rows per thread
  float acc[8];
#pragma unroll
  for (int r = 0; r < 8; ++r) acc[r] = 0.f;
#pragma unroll 8
  for (int k = 0; k < F_IN; ++k) {
    const float wv = W[k * F_OUT + c];
    const float4 x0 = *(const float4*)(&hT[k][rg * 8]);      // lane-uniform -> broadcast
    const float4 x1 = *(const float4*)(&hT[k][rg * 8 + 4]);
    acc[0] = fmaf(x0.x, wv, acc[0]); acc[1] = fmaf(x0.y, wv, acc[1]);
    acc[2] = fmaf(x0.z, wv, acc[2]); acc[3] = fmaf(x0.w, wv, acc[3]);
    acc[4] = fmaf(x1.x, wv, acc[4]); acc[5] = fmaf(x1.y, wv, acc[5]);
    acc[6] = fmaf(x1.z, wv, acc[6]); acc[7] = fmaf(x1.w, wv, acc[7]);
  }
  union { _Float16 hh[8]; uint4 u4; } pk;
#pragma unroll
  for (int r = 0; r < 8; ++r) pk.hh[r] = (_Float16)acc[r];
  *(uint4*)(g_WhT + (size_t)c * N_NODES + i0 + rg * 8) = pk.u4;

  // fused f12: f1[row] = sum_c Wh[row][c]*a1[c]  (rows live in acc[])
  const float a1c = a[c];
  const float a2c = a[F_OUT + c];
  float p1[8], p2[8];
#pragma unroll
  for (int r = 0; r < 8; ++r) { p1[r] = acc[r] * a1c; p2[r] = acc[r] * a2c; }
#pragma unroll
  for (int o = 32; o > 0; o >>= 1)
#pragma unroll
    for (int r = 0; r < 8; ++r) {
      p1[r] += __shfl_down(p1[r], o, 64);
      p2[r] += __shfl_down(p2[r], o, 64);
    }
  const int wv = t >> 6;
  const int lane = t & 63;
  if (lane == 0) {
#pragma unroll
    for (int r = 0; r < 8; ++r) {
      fs[wv >> 1][wv & 1][r][0] = p1[r];
      fs[wv >> 1][wv & 1][r][1] = p2[r];
    }
  }
  __syncthreads();
  if (t < 16) {
    const int rg2 = t >> 3, r2 = t & 7;
    g_f1[i0 + rg2 * 8 + r2] = fs[rg2][0][r2][0] + fs[rg2][1][r2][0];
    g_f2[i0 + rg2 * 8 + r2] = fs[rg2][0][r2][1] + fs[rg2][1][r2][1];
  }
}

// ---------------- Kernel C: fused attention (partials) ----------------
__device__ __forceinline__ float score_b(unsigned int bit, float f2v, float f1r) {
  float s = f1r + f2v;
  s = fmaxf(s, 0.2f * s);  // leaky_relu, alpha=0.2<1
  float arg = bit ? fmaf(s, 1.44269504088896f, -16.0f) : -1.0e5f;
  return __builtin_amdgcn_exp2f(arg);  // masked -> 0; 2^-16 scale cancels in num/den
}

__global__ __launch_bounds__(512, 2) void gat_attn_kernel() {
  const int t = threadIdx.x;
  const int wave = t >> 6;       // 0..7
  const int lane = t & 63;
  const int mrow = lane & 15;
  const int quad = lane >> 4;
  const int bid = blockIdx.x;
  const int jt = bid >> 5;       // 0..31
  const int ig = bid & 31;       // 0..31
  const int rowb = ig * 256 + wave * 32;

  __shared__ _Float16 ldsWhT[F_OUT * LDS_STRIDE];  // 67.6 KB, padded rows
  __shared__ float ldsF2[JTW];                     // 1 KB

  // early global issues (consumed after barrier; latency fully hidden)
  const int r0 = rowb + mrow, r1 = rowb + 16 + mrow;
  const uint2 AB0 = *(const uint2*)(g_bits + (size_t)r0 * 1024 + quad * 256 + jt * 8);
  const uint2 AB1 = *(const uint2*)(g_bits + (size_t)r1 * 1024 + quad * 256 + jt * 8);
  const float f1r0 = g_f1[r0];
  const float f1r1 = g_f1[r1];

  // runtime C/D layout probe: D1[m][n]=m, D2[m][n]=n (self-correcting scatter)
  int rm[4], cm[4];
  {
    half8 a1f, b1f, a2f, b2f;
#pragma unroll
    for (int e = 0; e < 8; ++e) {
      a1f[e] = (_Float16)0; b1f[e] = (_Float16)0;
      a2f[e] = (_Float16)0; b2f[e] = (_Float16)0;
    }
    if (quad == 0) {
      a1f[0] = (_Float16)mrow; b1f[0] = (_Float16)1;
      a2f[0] = (_Float16)1;    b2f[0] = (_Float16)mrow;
    }
    floatx4 d1 = (floatx4)0.f, d2 = (floatx4)0.f;
    d1 = __builtin_amdgcn_mfma_f32_16x16x32_f16(a1f, b1f, d1, 0, 0, 0);
    d2 = __builtin_amdgcn_mfma_f32_16x16x32_f16(a2f, b2f, d2, 0, 0, 0);
#pragma unroll
    for (int r = 0; r < 4; ++r) { rm[r] = (int)d1[r]; cm[r] = (int)d2[r]; }
  }

  // stage WhT tile: 128 rows x 256 halfs, padded LDS rows (stride 264)
#pragma unroll
  for (int it = 0; it < 8; ++it) {
    const int idx = it * 512 + t;
    const int row = idx >> 5, cu = idx & 31;
    *(half8*)&ldsWhT[row * LDS_STRIDE + cu * 8] =
        *(const half8*)(g_WhT + (size_t)row * N_NODES + jt * JTW + cu * 8);
  }
  if (t < 64) *(float4*)&ldsF2[t * 4] = *(const float4*)(g_f2 + jt * JTW + t * 4);
  __syncthreads();

  half8 ones;
#pragma unroll
  for (int e = 0; e < 8; ++e) ones[e] = (_Float16)1;

  floatx4 acc[2][8];
  floatx4 asum[2];
#pragma unroll
  for (int tl = 0; tl < 2; ++tl) {
    asum[tl] = (floatx4)0.f;
#pragma unroll
    for (int ct = 0; ct < 8; ++ct) acc[tl][ct] = (floatx4)0.f;
  }

  // main loop: 8 chunks of 32 j, pure LDS + VALU + MFMA (no global, no barrier)
#pragma unroll
  for (int ch = 0; ch < NCH; ++ch) {
    const int kb = ch * 32 + quad * 8;     // half-index within tile

    half8 bfr[8];
#pragma unroll
    for (int ct = 0; ct < 8; ++ct)
      bfr[ct] = *(const half8*)&ldsWhT[(ct * 16 + mrow) * LDS_STRIDE + kb];

    const float4 F0 = *(const float4*)&ldsF2[kb];
    const float4 F1 = *(const float4*)&ldsF2[kb + 4];

    const unsigned int b0 = ((ch & 4) ? AB0.y : AB0.x) >> ((ch & 3) * 8);
    const unsigned int b1 = ((ch & 4) ? AB1.y : AB1.x) >> ((ch & 3) * 8);

    half8 af0, af1;
    af0[0] = (_Float16)score_b(b0 & 1u,   F0.x, f1r0);
    af0[1] = (_Float16)score_b(b0 & 2u,   F0.y, f1r0);
    af0[2] = (_Float16)score_b(b0 & 4u,   F0.z, f1r0);
    af0[3] = (_Float16)score_b(b0 & 8u,   F0.w, f1r0);
    af0[4] = (_Float16)score_b(b0 & 16u,  F1.x, f1r0);
    af0[5] = (_Float16)score_b(b0 & 32u,  F1.y, f1r0);
    af0[6] = (_Float16)score_b(b0 & 64u,  F1.z, f1r0);
    af0[7] = (_Float16)score_b(b0 & 128u, F1.w, f1r0);
    af1[0] = (_Float16)score_b(b1 & 1u,   F0.x, f1r1);
    af1[1] = (_Float16)score_b(b1 & 2u,   F0.y, f1r1);
    af1[2] = (_Float16)score_b(b1 & 4u,   F0.z, f1r1);
    af1[3] = (_Float16)score_b(b1 & 8u,   F0.w, f1r1);
    af1[4] = (_Float16)score_b(b1 & 16u,  F1.x, f1r1);
    af1[5] = (_Float16)score_b(b1 & 32u,  F1.y, f1r1);
    af1[6] = (_Float16)score_b(b1 & 64u,  F1.z, f1r1);
    af1[7] = (_Float16)score_b(b1 & 128u, F1.w, f1r1);

#pragma unroll
    for (int ct = 0; ct < 8; ++ct) {
      acc[0][ct] = __builtin_amdgcn_mfma_f32_16x16x32_f16(af0, bfr[ct], acc[0][ct], 0, 0, 0);
      acc[1][ct] = __builtin_amdgcn_mfma_f32_16x16x32_f16(af1, bfr[ct], acc[1][ct], 0, 0, 0);
    }
    asum[0] = __builtin_amdgcn_mfma_f32_16x16x32_f16(af0, ones, asum[0], 0, 0, 0);
    asum[1] = __builtin_amdgcn_mfma_f32_16x16x32_f16(af1, ones, asum[1], 0, 0, 0);
  }

  // epilogue: waves own disjoint rows -> direct stores, no cross-wave reduce
  float* pslice = g_part[jt];
#pragma unroll
  for (int tl = 0; tl < 2; ++tl)
#pragma unroll
    for (int ct = 0; ct < 8; ++ct)
#pragma unroll
      for (int r = 0; r < 4; ++r)
        pslice[(size_t)(rowb + tl * 16 + rm[r]) * F_OUT + ct * 16 + cm[r]] =
            acc[tl][ct][r];
  if (mrow == 0) {
#pragma unroll
    for (int tl = 0; tl < 2; ++tl)
#pragma unroll
      for (int r = 0; r < 4; ++r)
        g_spart[jt][rowb + tl * 16 + rm[r]] = asum[tl][r];
  }
}

// ---------------- Kernel D: combine partials + normalize ----------------
__global__ __launch_bounds__(256) void comb_kernel(float* __restrict__ out) {
  const int u = blockIdx.x * 256 + threadIdx.x;  // float4 unit
  const int row = u >> 5;                        // 32 float4 per row
  float s = 0.f;
  f32x4 v = (f32x4)0.f;
#pragma unroll
  for (int q = 0; q < NJT; ++q) {
    s += g_spart[q][row];
    v += *(((const f32x4*)g_part[q]) + u);
  }
  __builtin_nontemporal_store(v * (1.0f / s), ((f32x4*)out) + u);
}

extern "C" void kernel_launch(void* const* d_in, const int* in_sizes, int n_in,
                              void* d_out, int out_size, void* d_ws, size_t ws_size,
                              hipStream_t stream) {
  const float* h = (const float*)d_in[0];
  const int* adj = (const int*)d_in[1];
  const float* W = (const float*)d_in[2];
  const float* a = (const float*)d_in[3];
  float* out = (float*)d_out;
  (void)d_ws; (void)ws_size;

  prep_kernel<<<dim3(1536), dim3(256), 0, stream>>>(adj, h, W, a);
  gat_attn_kernel<<<dim3(NJT * 32), dim3(512), 0, stream>>>();
  comb_kernel<<<dim3(N_NODES * F_OUT / 4 / 256), dim3(256), 0, stream>>>(out);
}

// Round 7
// 411.246 us; speedup vs baseline: 1.3073x; 1.0504x over previous
//
#include <hip/hip_runtime.h>

// GAT layer, N=8192, F_IN=256, F_OUT=128.
// K0 prep (role-interleaved by bid%3 so pack(memory) || wh(VALU) co-run):
//   pack: adj (268 MB, 1 bit info/elem) -> g_bits (8 MB), nt coalesced reads.
//     Layout: byte for j-chunk b of row r at r*1024 + (b&3)*256 + (b>>2), so an
//     attn thread's chunk-bytes for (row, quad, 2 j-tiles) are one uint4.
//   wh: Wh = h@W (fp32 VALU) -> WhT (f16 [c][j]) + f1/f2 fused reduction.
// K1 attn: zero in-loop global loads (R5 lesson). Block = 512 thr, 8 waves x
//   16 rows (acc[8] only -> ~105 VGPR, launch_bounds(512,4) -> 2 blocks/CU,
//   16 waves/CU; R6's 32-row waves needed ~150 VGPR -> 1 block/CU).
//   Each block: 128 rows x TWO 256-col j-tiles (restage LDS once between
//   tiles, acc accumulates across tiles -> 16 partial slices = 64 MB instead
//   of R6's 32/128 MB). WhT tile in LDS (padded stride 264), bits = 1 uint4.
//   Static C/D map (row=quad*4+r, col=mrow; HW-verified) replaces probe.
// K2 comb: sum 16 partial slices / sum 16 spart.

#define N_NODES 8192
#define F_IN 256
#define F_OUT 128
#define NJT 32            // j-tiles of 256
#define JTW 256           // j-tile width
#define NCH 8             // 32-wide chunks per tile
#define NSL 16            // partial slices (2 tiles merged per block)
#define LDS_STRIDE 264    // 256 + 8 halfs pad

typedef _Float16 half8 __attribute__((ext_vector_type(8)));
typedef float floatx4 __attribute__((ext_vector_type(4)));
typedef float f32x4 __attribute__((ext_vector_type(4)));
typedef int intx4 __attribute__((ext_vector_type(4)));

__device__ __align__(16) _Float16 g_WhT[(size_t)F_OUT * N_NODES];      // 2 MB
__device__ __align__(16) float g_f1[N_NODES];
__device__ __align__(16) float g_f2[N_NODES];
__device__ __align__(16) float g_part[NSL][N_NODES * F_OUT];           // 64 MB
__device__ __align__(16) float g_spart[NSL][N_NODES];                  // 512 KB
__device__ __align__(16) unsigned char g_bits[(size_t)N_NODES * (N_NODES / 8)]; // 8 MB

// ---------------- Kernel 0: pack(adj->bits) || wh(+f12) ----------------
__global__ __launch_bounds__(256, 2) void prep_kernel(
    const int* __restrict__ adj, const float* __restrict__ h,
    const float* __restrict__ W, const float* __restrict__ a) {
  const int t = threadIdx.x;
  const int bid = blockIdx.x;

  if (bid % 3 != 0) {
    // ---- pack role: 8 rows per block, fully coalesced nt reads ----
    const int pid = bid - (bid + 2) / 3;   // 0..1023
    const int wave = t >> 6;
    const int lane = t & 63;
    const int row0 = pid * 8 + wave * 2;
#pragma unroll 1
    for (int rr = 0; rr < 2; ++rr) {
      const int r = row0 + rr;
      const int* rowp = adj + (size_t)r * N_NODES;
#pragma unroll 4
      for (int p = 0; p < 16; ++p) {
        const int j0 = p * 512 + lane * 8;   // wave reads 2 KB contiguous/pass
        const intx4 v0 = __builtin_nontemporal_load((const intx4*)(rowp + j0));
        const intx4 v1 = __builtin_nontemporal_load((const intx4*)(rowp + j0 + 4));
        unsigned int byte = 0;
        byte |= (v0.x != 0) ? 1u : 0u;
        byte |= (v0.y != 0) ? 2u : 0u;
        byte |= (v0.z != 0) ? 4u : 0u;
        byte |= (v0.w != 0) ? 8u : 0u;
        byte |= (v1.x != 0) ? 16u : 0u;
        byte |= (v1.y != 0) ? 32u : 0u;
        byte |= (v1.z != 0) ? 64u : 0u;
        byte |= (v1.w != 0) ? 128u : 0u;
        const int b = p * 64 + lane;         // 8-j chunk index within row
        g_bits[(size_t)r * 1024 + (b & 3) * 256 + (b >> 2)] = (unsigned char)byte;
      }
    }
    return;
  }

  // ---- wh role: 16 rows per block + fused f1/f2 ----
  __shared__ float hT[F_IN][20];  // pad 20 keeps &hT[k][rg*8] 16B-aligned
  __shared__ float fs[2][2][8][2];
  const int i0 = (bid / 3) * 16;
  {
    const int row = t >> 4;   // 0..15
    const int fu = t & 15;    // float4 unit
#pragma unroll
    for (int r = 0; r < 4; ++r) {
      const int ku = r * 16 + fu;  // 0..63
      const f32x4 v = __builtin_nontemporal_load(
          (const f32x4*)(h + (size_t)(i0 + row) * F_IN + ku * 4));
      hT[ku * 4 + 0][row] = v.x; hT[ku * 4 + 1][row] = v.y;
      hT[ku * 4 + 2][row] = v.z; hT[ku * 4 + 3][row] = v.w;
    }
  }
  __syncthreads();
  const int c = t & 127;
  const int rg = t >> 7;   // 8 rows per thread
  float acc[8];
#pragma unroll
  for (int r = 0; r < 8; ++r) acc[r] = 0.f;
#pragma unroll 8
  for (int k = 0; k < F_IN; ++k) {
    const float wv = W[k * F_OUT + c];
    const float4 x0 = *(const float4*)(&hT[k][rg * 8]);      // lane-uniform -> broadcast
    const float4 x1 = *(const float4*)(&hT[k][rg * 8 + 4]);
    acc[0] = fmaf(x0.x, wv, acc[0]); acc[1] = fmaf(x0.y, wv, acc[1]);
    acc[2] = fmaf(x0.z, wv, acc[2]); acc[3] = fmaf(x0.w, wv, acc[3]);
    acc[4] = fmaf(x1.x, wv, acc[4]); acc[5] = fmaf(x1.y, wv, acc[5]);
    acc[6] = fmaf(x1.z, wv, acc[6]); acc[7] = fmaf(x1.w, wv, acc[7]);
  }
  union { _Float16 hh[8]; uint4 u4; } pk;
#pragma unroll
  for (int r = 0; r < 8; ++r) pk.hh[r] = (_Float16)acc[r];
  *(uint4*)(g_WhT + (size_t)c * N_NODES + i0 + rg * 8) = pk.u4;

  // fused f12: f1[row] = sum_c Wh[row][c]*a1[c]  (rows live in acc[])
  const float a1c = a[c];
  const float a2c = a[F_OUT + c];
  float p1[8], p2[8];
#pragma unroll
  for (int r = 0; r < 8; ++r) { p1[r] = acc[r] * a1c; p2[r] = acc[r] * a2c; }
#pragma unroll
  for (int o = 32; o > 0; o >>= 1)
#pragma unroll
    for (int r = 0; r < 8; ++r) {
      p1[r] += __shfl_down(p1[r], o, 64);
      p2[r] += __shfl_down(p2[r], o, 64);
    }
  const int wv = t >> 6;
  const int lane = t & 63;
  if (lane == 0) {
#pragma unroll
    for (int r = 0; r < 8; ++r) {
      fs[wv >> 1][wv & 1][r][0] = p1[r];
      fs[wv >> 1][wv & 1][r][1] = p2[r];
    }
  }
  __syncthreads();
  if (t < 16) {
    const int rg2 = t >> 3, r2 = t & 7;
    g_f1[i0 + rg2 * 8 + r2] = fs[rg2][0][r2][0] + fs[rg2][1][r2][0];
    g_f2[i0 + rg2 * 8 + r2] = fs[rg2][0][r2][1] + fs[rg2][1][r2][1];
  }
}

// ---------------- Kernel C: fused attention (partials) ----------------
__device__ __forceinline__ float score_b(unsigned int bit, float f2v, float f1r) {
  float s = f1r + f2v;
  s = fmaxf(s, 0.2f * s);  // leaky_relu, alpha=0.2<1
  float arg = bit ? fmaf(s, 1.44269504088896f, -16.0f) : -1.0e5f;
  return __builtin_amdgcn_exp2f(arg);  // masked -> 0; 2^-16 scale cancels in num/den
}

__global__ __launch_bounds__(512, 4) void gat_attn_kernel() {
  const int t = threadIdx.x;
  const int wave = t >> 6;       // 0..7
  const int lane = t & 63;
  const int mrow = lane & 15;
  const int quad = lane >> 4;
  const int bid = blockIdx.x;
  const int jtg = bid >> 6;      // 0..15 (pair of j-tiles)
  const int ig = bid & 63;       // 0..63
  const int rowb = ig * 128 + wave * 16;   // 16 rows per wave

  __shared__ _Float16 ldsWhT[F_OUT * LDS_STRIDE];  // 67.6 KB, padded rows
  __shared__ float ldsF2[JTW];                     // 1 KB

  // early global issues (consumed after barrier; latency hidden by staging)
  const int r0 = rowb + mrow;
  const uint4 AB = *(const uint4*)(g_bits + (size_t)r0 * 1024 + quad * 256 + jtg * 16);
  const float f1r0 = g_f1[r0];

  half8 ones;
#pragma unroll
  for (int e = 0; e < 8; ++e) ones[e] = (_Float16)1;

  floatx4 acc[8];
  floatx4 asum = (floatx4)0.f;
#pragma unroll
  for (int ct = 0; ct < 8; ++ct) acc[ct] = (floatx4)0.f;

#pragma unroll
  for (int tp = 0; tp < 2; ++tp) {
    const int jt = jtg * 2 + tp;
    if (tp) __syncthreads();   // all waves done reading tile 0 before overwrite

    // stage WhT tile: 128 rows x 256 halfs, padded LDS rows (stride 264)
#pragma unroll
    for (int it = 0; it < 8; ++it) {
      const int idx = it * 512 + t;
      const int row = idx >> 5, cu = idx & 31;
      *(half8*)&ldsWhT[row * LDS_STRIDE + cu * 8] =
          *(const half8*)(g_WhT + (size_t)row * N_NODES + jt * JTW + cu * 8);
    }
    if (t < 64) *(float4*)&ldsF2[t * 4] = *(const float4*)(g_f2 + jt * JTW + t * 4);
    __syncthreads();

    // 8 chunks of 32 j: pure LDS + VALU + MFMA (no global, no barrier)
#pragma unroll
    for (int ch = 0; ch < NCH; ++ch) {
      const int kb = ch * 32 + quad * 8;     // half-index within tile

      half8 bfr[8];
#pragma unroll
      for (int ct = 0; ct < 8; ++ct)
        bfr[ct] = *(const half8*)&ldsWhT[(ct * 16 + mrow) * LDS_STRIDE + kb];

      const float4 F0 = *(const float4*)&ldsF2[kb];
      const float4 F1 = *(const float4*)&ldsF2[kb + 4];

      const unsigned int dw = tp ? ((ch & 4) ? AB.w : AB.z)
                                 : ((ch & 4) ? AB.y : AB.x);
      const unsigned int b0 = dw >> ((ch & 3) * 8);

      half8 af0;
      af0[0] = (_Float16)score_b(b0 & 1u,   F0.x, f1r0);
      af0[1] = (_Float16)score_b(b0 & 2u,   F0.y, f1r0);
      af0[2] = (_Float16)score_b(b0 & 4u,   F0.z, f1r0);
      af0[3] = (_Float16)score_b(b0 & 8u,   F0.w, f1r0);
      af0[4] = (_Float16)score_b(b0 & 16u,  F1.x, f1r0);
      af0[5] = (_Float16)score_b(b0 & 32u,  F1.y, f1r0);
      af0[6] = (_Float16)score_b(b0 & 64u,  F1.z, f1r0);
      af0[7] = (_Float16)score_b(b0 & 128u, F1.w, f1r0);

#pragma unroll
      for (int ct = 0; ct < 8; ++ct)
        acc[ct] = __builtin_amdgcn_mfma_f32_16x16x32_f16(af0, bfr[ct], acc[ct], 0, 0, 0);
      asum = __builtin_amdgcn_mfma_f32_16x16x32_f16(af0, ones, asum, 0, 0, 0);
    }
  }

  // epilogue: static C/D map (row = quad*4+r, col = mrow), disjoint rows
  float* pslice = g_part[jtg];
#pragma unroll
  for (int ct = 0; ct < 8; ++ct)
#pragma unroll
    for (int r = 0; r < 4; ++r)
      pslice[(size_t)(rowb + quad * 4 + r) * F_OUT + ct * 16 + mrow] = acc[ct][r];
  if (mrow == 0) {
#pragma unroll
    for (int r = 0; r < 4; ++r)
      g_spart[jtg][rowb + quad * 4 + r] = asum[r];
  }
}

// ---------------- Kernel D: combine partials + normalize ----------------
__global__ __launch_bounds__(256) void comb_kernel(float* __restrict__ out) {
  const int u = blockIdx.x * 256 + threadIdx.x;  // float4 unit
  const int row = u >> 5;                        // 32 float4 per row
  float s = 0.f;
  f32x4 v = (f32x4)0.f;
#pragma unroll
  for (int q = 0; q < NSL; ++q) {
    s += g_spart[q][row];
    v += *(((const f32x4*)g_part[q]) + u);
  }
  __builtin_nontemporal_store(v * (1.0f / s), ((f32x4*)out) + u);
}

extern "C" void kernel_launch(void* const* d_in, const int* in_sizes, int n_in,
                              void* d_out, int out_size, void* d_ws, size_t ws_size,
                              hipStream_t stream) {
  const float* h = (const float*)d_in[0];
  const int* adj = (const int*)d_in[1];
  const float* W = (const float*)d_in[2];
  const float* a = (const float*)d_in[3];
  float* out = (float*)d_out;
  (void)d_ws; (void)ws_size;

  prep_kernel<<<dim3(1536), dim3(256), 0, stream>>>(adj, h, W, a);
  gat_attn_kernel<<<dim3(64 * NSL), dim3(512), 0, stream>>>();
  comb_kernel<<<dim3(N_NODES * F_OUT / 4 / 256), dim3(256), 0, stream>>>(out);
}

// Round 8
// 406.145 us; speedup vs baseline: 1.3237x; 1.0126x over previous
//
#include <hip/hip_runtime.h>

// GAT layer, N=8192, F_IN=256, F_OUT=128.
// K0 prep (role-interleaved by bid%3 so pack(memory) || wh(VALU) co-run):
//   pack: adj (268 MB, 1 bit info/elem) -> g_bits (8 MB), nt coalesced reads.
//     Layout: byte for j-chunk b of row r at r*1024 + (b&3)*256 + (b>>2), so an
//     attn thread's chunk-bytes for (row, quad, 4 j-tiles) are 2 aligned uint4.
//   wh: Wh = h@W (fp32 VALU) -> WhT (f16 [c][j]) + f1/f2 fused reduction.
// K1 attn: zero in-loop global loads. Block = 512 thr, 8 waves x 16 rows
//   (acc[8] -> ~105 VGPR, launch_bounds(512,4) -> 2 blocks/CU). Each block:
//   128 rows x FOUR 256-col j-tiles (restage LDS between tiles, acc
//   accumulates across -> 8 partial slices = 32 MB; R7 had 16/64 MB).
//   Grid 512 = exactly 2/CU: one residency round, no tail. WhT tile in LDS
//   (padded stride 264), static C/D map (row=quad*4+r, col=mrow).
// K2 comb: sum 8 partial slices / sum 8 spart, nt loads.

#define N_NODES 8192
#define F_IN 256
#define F_OUT 128
#define JTW 256           // j-tile width
#define NCH 8             // 32-wide chunks per tile
#define TPB 4             // j-tiles per block
#define NSL 8             // partial slices
#define LDS_STRIDE 264    // 256 + 8 halfs pad

typedef _Float16 half8 __attribute__((ext_vector_type(8)));
typedef float floatx4 __attribute__((ext_vector_type(4)));
typedef float f32x4 __attribute__((ext_vector_type(4)));
typedef int intx4 __attribute__((ext_vector_type(4)));

__device__ __align__(16) _Float16 g_WhT[(size_t)F_OUT * N_NODES];      // 2 MB
__device__ __align__(16) float g_f1[N_NODES];
__device__ __align__(16) float g_f2[N_NODES];
__device__ __align__(16) float g_part[NSL][N_NODES * F_OUT];           // 32 MB
__device__ __align__(16) float g_spart[NSL][N_NODES];                  // 256 KB
__device__ __align__(16) unsigned char g_bits[(size_t)N_NODES * (N_NODES / 8)]; // 8 MB

// ---------------- Kernel 0: pack(adj->bits) || wh(+f12) ----------------
__global__ __launch_bounds__(256, 2) void prep_kernel(
    const int* __restrict__ adj, const float* __restrict__ h,
    const float* __restrict__ W, const float* __restrict__ a) {
  const int t = threadIdx.x;
  const int bid = blockIdx.x;

  if (bid % 3 != 0) {
    // ---- pack role: 8 rows per block, fully coalesced nt reads ----
    const int pid = bid - (bid + 2) / 3;   // 0..1023
    const int wave = t >> 6;
    const int lane = t & 63;
    const int row0 = pid * 8 + wave * 2;
#pragma unroll 1
    for (int rr = 0; rr < 2; ++rr) {
      const int r = row0 + rr;
      const int* rowp = adj + (size_t)r * N_NODES;
#pragma unroll 4
      for (int p = 0; p < 16; ++p) {
        const int j0 = p * 512 + lane * 8;   // wave reads 2 KB contiguous/pass
        const intx4 v0 = __builtin_nontemporal_load((const intx4*)(rowp + j0));
        const intx4 v1 = __builtin_nontemporal_load((const intx4*)(rowp + j0 + 4));
        unsigned int byte = 0;
        byte |= (v0.x != 0) ? 1u : 0u;
        byte |= (v0.y != 0) ? 2u : 0u;
        byte |= (v0.z != 0) ? 4u : 0u;
        byte |= (v0.w != 0) ? 8u : 0u;
        byte |= (v1.x != 0) ? 16u : 0u;
        byte |= (v1.y != 0) ? 32u : 0u;
        byte |= (v1.z != 0) ? 64u : 0u;
        byte |= (v1.w != 0) ? 128u : 0u;
        const int b = p * 64 + lane;         // 8-j chunk index within row
        g_bits[(size_t)r * 1024 + (b & 3) * 256 + (b >> 2)] = (unsigned char)byte;
      }
    }
    return;
  }

  // ---- wh role: 16 rows per block + fused f1/f2 ----
  __shared__ float hT[F_IN][20];  // pad 20 keeps &hT[k][rg*8] 16B-aligned
  __shared__ float fs[2][2][8][2];
  const int i0 = (bid / 3) * 16;
  {
    const int row = t >> 4;   // 0..15
    const int fu = t & 15;    // float4 unit
#pragma unroll
    for (int r = 0; r < 4; ++r) {
      const int ku = r * 16 + fu;  // 0..63
      const f32x4 v = __builtin_nontemporal_load(
          (const f32x4*)(h + (size_t)(i0 + row) * F_IN + ku * 4));
      hT[ku * 4 + 0][row] = v.x; hT[ku * 4 + 1][row] = v.y;
      hT[ku * 4 + 2][row] = v.z; hT[ku * 4 + 3][row] = v.w;
    }
  }
  __syncthreads();
  const int c = t & 127;
  const int rg = t >> 7;   // 8 rows per thread
  float acc[8];
#pragma unroll
  for (int r = 0; r < 8; ++r) acc[r] = 0.f;
#pragma unroll 8
  for (int k = 0; k < F_IN; ++k) {
    const float wv = W[k * F_OUT + c];
    const float4 x0 = *(const float4*)(&hT[k][rg * 8]);      // lane-uniform -> broadcast
    const float4 x1 = *(const float4*)(&hT[k][rg * 8 + 4]);
    acc[0] = fmaf(x0.x, wv, acc[0]); acc[1] = fmaf(x0.y, wv, acc[1]);
    acc[2] = fmaf(x0.z, wv, acc[2]); acc[3] = fmaf(x0.w, wv, acc[3]);
    acc[4] = fmaf(x1.x, wv, acc[4]); acc[5] = fmaf(x1.y, wv, acc[5]);
    acc[6] = fmaf(x1.z, wv, acc[6]); acc[7] = fmaf(x1.w, wv, acc[7]);
  }
  union { _Float16 hh[8]; uint4 u4; } pk;
#pragma unroll
  for (int r = 0; r < 8; ++r) pk.hh[r] = (_Float16)acc[r];
  *(uint4*)(g_WhT + (size_t)c * N_NODES + i0 + rg * 8) = pk.u4;

  // fused f12: f1[row] = sum_c Wh[row][c]*a1[c]  (rows live in acc[])
  const float a1c = a[c];
  const float a2c = a[F_OUT + c];
  float p1[8], p2[8];
#pragma unroll
  for (int r = 0; r < 8; ++r) { p1[r] = acc[r] * a1c; p2[r] = acc[r] * a2c; }
#pragma unroll
  for (int o = 32; o > 0; o >>= 1)
#pragma unroll
    for (int r = 0; r < 8; ++r) {
      p1[r] += __shfl_down(p1[r], o, 64);
      p2[r] += __shfl_down(p2[r], o, 64);
    }
  const int wv = t >> 6;
  const int lane = t & 63;
  if (lane == 0) {
#pragma unroll
    for (int r = 0; r < 8; ++r) {
      fs[wv >> 1][wv & 1][r][0] = p1[r];
      fs[wv >> 1][wv & 1][r][1] = p2[r];
    }
  }
  __syncthreads();
  if (t < 16) {
    const int rg2 = t >> 3, r2 = t & 7;
    g_f1[i0 + rg2 * 8 + r2] = fs[rg2][0][r2][0] + fs[rg2][1][r2][0];
    g_f2[i0 + rg2 * 8 + r2] = fs[rg2][0][r2][1] + fs[rg2][1][r2][1];
  }
}

// ---------------- Kernel C: fused attention (partials) ----------------
__device__ __forceinline__ float score_b(unsigned int bit, float f2v, float f1r) {
  float s = f1r + f2v;
  s = fmaxf(s, 0.2f * s);  // leaky_relu, alpha=0.2<1
  float arg = bit ? fmaf(s, 1.44269504088896f, -16.0f) : -1.0e5f;
  return __builtin_amdgcn_exp2f(arg);  // masked -> 0; 2^-16 scale cancels in num/den
}

__global__ __launch_bounds__(512, 4) void gat_attn_kernel() {
  const int t = threadIdx.x;
  const int wave = t >> 6;       // 0..7
  const int lane = t & 63;
  const int mrow = lane & 15;
  const int quad = lane >> 4;
  const int bid = blockIdx.x;
  const int jtg = bid >> 6;      // 0..7 (group of 4 j-tiles)
  const int ig = bid & 63;       // 0..63
  const int rowb = ig * 128 + wave * 16;   // 16 rows per wave

  __shared__ _Float16 ldsWhT[F_OUT * LDS_STRIDE];  // 67.6 KB, padded rows
  __shared__ float ldsF2[JTW];                     // 1 KB

  // early global issues (consumed after barrier; latency hidden by staging)
  const int r0 = rowb + mrow;
  const uint4 B0 = *(const uint4*)(g_bits + (size_t)r0 * 1024 + quad * 256 + jtg * 32);
  const uint4 B1 = *(const uint4*)(g_bits + (size_t)r0 * 1024 + quad * 256 + jtg * 32 + 16);
  const float f1r0 = g_f1[r0];
  unsigned int dws[8];
  dws[0] = B0.x; dws[1] = B0.y; dws[2] = B0.z; dws[3] = B0.w;
  dws[4] = B1.x; dws[5] = B1.y; dws[6] = B1.z; dws[7] = B1.w;

  half8 ones;
#pragma unroll
  for (int e = 0; e < 8; ++e) ones[e] = (_Float16)1;

  floatx4 acc[8];
  floatx4 asum = (floatx4)0.f;
#pragma unroll
  for (int ct = 0; ct < 8; ++ct) acc[ct] = (floatx4)0.f;

#pragma unroll
  for (int tp = 0; tp < TPB; ++tp) {
    const int jt = jtg * TPB + tp;
    if (tp) __syncthreads();   // all waves done reading prev tile before overwrite

    // stage WhT tile: 128 rows x 256 halfs, padded LDS rows (stride 264)
#pragma unroll
    for (int it = 0; it < 8; ++it) {
      const int idx = it * 512 + t;
      const int row = idx >> 5, cu = idx & 31;
      *(half8*)&ldsWhT[row * LDS_STRIDE + cu * 8] =
          *(const half8*)(g_WhT + (size_t)row * N_NODES + jt * JTW + cu * 8);
    }
    if (t < 64) *(float4*)&ldsF2[t * 4] = *(const float4*)(g_f2 + jt * JTW + t * 4);
    __syncthreads();

    // 8 chunks of 32 j: pure LDS + VALU + MFMA (no global, no barrier)
#pragma unroll
    for (int ch = 0; ch < NCH; ++ch) {
      const int kb = ch * 32 + quad * 8;     // half-index within tile

      half8 bfr[8];
#pragma unroll
      for (int ct = 0; ct < 8; ++ct)
        bfr[ct] = *(const half8*)&ldsWhT[(ct * 16 + mrow) * LDS_STRIDE + kb];

      const float4 F0 = *(const float4*)&ldsF2[kb];
      const float4 F1 = *(const float4*)&ldsF2[kb + 4];

      // dws index is compile-time (tp, ch fully unrolled) -> stays in VGPRs
      const unsigned int b0 = dws[tp * 2 + (ch >> 2)] >> ((ch & 3) * 8);

      half8 af0;
      af0[0] = (_Float16)score_b(b0 & 1u,   F0.x, f1r0);
      af0[1] = (_Float16)score_b(b0 & 2u,   F0.y, f1r0);
      af0[2] = (_Float16)score_b(b0 & 4u,   F0.z, f1r0);
      af0[3] = (_Float16)score_b(b0 & 8u,   F0.w, f1r0);
      af0[4] = (_Float16)score_b(b0 & 16u,  F1.x, f1r0);
      af0[5] = (_Float16)score_b(b0 & 32u,  F1.y, f1r0);
      af0[6] = (_Float16)score_b(b0 & 64u,  F1.z, f1r0);
      af0[7] = (_Float16)score_b(b0 & 128u, F1.w, f1r0);

#pragma unroll
      for (int ct = 0; ct < 8; ++ct)
        acc[ct] = __builtin_amdgcn_mfma_f32_16x16x32_f16(af0, bfr[ct], acc[ct], 0, 0, 0);
      asum = __builtin_amdgcn_mfma_f32_16x16x32_f16(af0, ones, asum, 0, 0, 0);
    }
  }

  // epilogue: static C/D map (row = quad*4+r, col = mrow), disjoint rows
  float* pslice = g_part[jtg];
#pragma unroll
  for (int ct = 0; ct < 8; ++ct)
#pragma unroll
    for (int r = 0; r < 4; ++r)
      pslice[(size_t)(rowb + quad * 4 + r) * F_OUT + ct * 16 + mrow] = acc[ct][r];
  if (mrow == 0) {
#pragma unroll
    for (int r = 0; r < 4; ++r)
      g_spart[jtg][rowb + quad * 4 + r] = asum[r];
  }
}

// ---------------- Kernel D: combine partials + normalize ----------------
__global__ __launch_bounds__(256) void comb_kernel(float* __restrict__ out) {
  const int u = blockIdx.x * 256 + threadIdx.x;  // float4 unit
  const int row = u >> 5;                        // 32 float4 per row
  float s = 0.f;
  f32x4 v = (f32x4)0.f;
#pragma unroll
  for (int q = 0; q < NSL; ++q) {
    s += g_spart[q][row];
    v += __builtin_nontemporal_load(((const f32x4*)g_part[q]) + u);
  }
  __builtin_nontemporal_store(v * (1.0f / s), ((f32x4*)out) + u);
}

extern "C" void kernel_launch(void* const* d_in, const int* in_sizes, int n_in,
                              void* d_out, int out_size, void* d_ws, size_t ws_size,
                              hipStream_t stream) {
  const float* h = (const float*)d_in[0];
  const int* adj = (const int*)d_in[1];
  const float* W = (const float*)d_in[2];
  const float* a = (const float*)d_in[3];
  float* out = (float*)d_out;
  (void)d_ws; (void)ws_size;

  prep_kernel<<<dim3(1536), dim3(256), 0, stream>>>(adj, h, W, a);
  gat_attn_kernel<<<dim3(64 * NSL), dim3(512), 0, stream>>>();
  comb_kernel<<<dim3(N_NODES * F_OUT / 4 / 256), dim3(256), 0, stream>>>(out);
}